// Round 1
// baseline (389.360 us; speedup 1.0000x reference)
//
#include <hip/hip_runtime.h>

#define DELTA 1e-6f

// sizes: b=64, m=1024, w=64, r=4, d=512, iface=471
#define NB 64
#define NM 1024
#define NW 64
#define NR 4
#define ND 512
#define NIF 471

__device__ __forceinline__ float sigmoidf_(float x){ return 1.0f/(1.0f+expf(-x)); }
__device__ __forceinline__ float softplusf_(float x){ return fmaxf(x,0.0f) + log1pf(expf(-fabsf(x))); }

__device__ __forceinline__ float waveSum(float v){
  #pragma unroll
  for(int o=32;o>0;o>>=1) v += __shfl_down(v,o,64);
  return v;
}
__device__ __forceinline__ float waveMax(float v){
  #pragma unroll
  for(int o=32;o>0;o>>=1) v = fmaxf(v, __shfl_down(v,o,64));
  return v;
}

// ---------------- K1: iface = xi @ W + bW ----------------
__global__ __launch_bounds__(256) void k_iface(const float* __restrict__ xi,
                                               const float* __restrict__ Wm,
                                               const float* __restrict__ bW,
                                               float* __restrict__ iface){
  int b = blockIdx.x;
  __shared__ float xs[ND];
  for(int k=threadIdx.x;k<ND;k+=256) xs[k]=xi[b*ND+k];
  __syncthreads();
  for(int c=threadIdx.x;c<NIF;c+=256){
    float acc = bW[c];
    #pragma unroll 4
    for(int k=0;k<ND;k++) acc = fmaf(xs[k], Wm[k*NIF+c], acc);
    iface[b*NIF+c]=acc;
  }
}

// ---------------- K2: usage/psi, write-content softmax, allocation (sort), new_write_w ----------------
__global__ __launch_bounds__(1024) void k_write(
    const float* __restrict__ iface, const float* __restrict__ mem,
    const float* __restrict__ rw_old, const float* __restrict__ ww_old,
    const float* __restrict__ uv, float* __restrict__ wwp){
  int b = blockIdx.x; int tid = threadIdx.x;
  int lane = tid & 63, wv = tid >> 6;
  __shared__ float wkey[NW];
  __shared__ unsigned long long skey[NM];
  __shared__ float fb[NM];
  __shared__ float fb2[NM];
  __shared__ float red[17];
  const float* ifb = iface + b*NIF;
  if (tid < NW) wkey[tid] = ifb[260+tid];
  __syncthreads();
  // per-batch scalars (computed redundantly)
  float sw = softplusf_(1.0f + fmaxf(ifb[324],0.0f));
  float ag = sigmoidf_(ifb[457]);
  float wg = sigmoidf_(ifb[458]);
  float fg0=sigmoidf_(ifb[453]), fg1=sigmoidf_(ifb[454]);
  float fg2=sigmoidf_(ifb[455]), fg3=sigmoidf_(ifb[456]);
  float kn=0.0f;
  for(int k=0;k<NW;k++){ float t=wkey[k]; kn += t*t; }
  kn = sqrtf(kn);
  int j = tid;
  // usage
  float u0  = uv[b*NM+j];
  float wwo = ww_old[b*NM+j];
  float usage = u0 + (1.0f-u0)*(1.0f - (1.0f-wwo));
  float psi = (1.0f - fg0*rw_old[(b*NR+0)*NM+j])
            * (1.0f - fg1*rw_old[(b*NR+1)*NM+j])
            * (1.0f - fg2*rw_old[(b*NR+2)*NM+j])
            * (1.0f - fg3*rw_old[(b*NR+3)*NM+j]);
  usage *= psi;
  // write-content logit: cosine(memory_row, write_key) * softplus(strength)
  float dot=0.0f, nrm=0.0f;
  const float* mrow = mem + ((size_t)b*NM + j)*NW;
  for(int k=0;k<NW;k++){ float mv=mrow[k]; dot = fmaf(mv,wkey[k],dot); nrm = fmaf(mv,mv,nrm); }
  float logit = sw * dot / ((sqrtf(nrm)+DELTA)*(kn+DELTA));
  // block softmax over 1024
  float m1 = waveMax(logit); if(lane==0) red[wv]=m1; __syncthreads();
  if(tid==0){ float mm=red[0]; for(int i=1;i<16;i++) mm=fmaxf(mm,red[i]); red[16]=mm; } __syncthreads();
  float e = expf(logit - red[16]);
  float s1 = waveSum(e); if(lane==0) red[wv]=s1; __syncthreads();
  if(tid==0){ float ss=0; for(int i=0;i<16;i++) ss+=red[i]; red[16]=ss; } __syncthreads();
  float wcw = e/red[16];
  // allocation: stable sort of u (ties by index), cumprod, scatter
  float u = DELTA + (1.0f-DELTA)*usage;
  skey[tid] = ((unsigned long long)__float_as_uint(u) << 32) | (unsigned)tid;
  __syncthreads();
  for(int k2=2;k2<=NM;k2<<=1){
    for(int jj=k2>>1;jj>0;jj>>=1){
      int ixj = tid ^ jj;
      if (ixj > tid){
        unsigned long long a=skey[tid], c=skey[ixj];
        bool asc = ((tid & k2)==0);
        bool doswap = asc ? (a>c) : (a<c);
        if (doswap){ skey[tid]=c; skey[ixj]=a; }
      }
      __syncthreads();
    }
  }
  float su = __uint_as_float((unsigned)(skey[tid]>>32));
  int phi  = (int)(skey[tid] & 0xffffffffu);
  fb[tid] = su; __syncthreads();
  // inclusive prefix product (Hillis-Steele)
  for(int d=1; d<NM; d<<=1){
    float o = (tid>=d)? fb[tid-d] : 1.0f;
    __syncthreads();
    fb[tid] *= o;
    __syncthreads();
  }
  float salloc = (1.0f - su)*fb[tid];
  fb2[phi] = salloc;
  __syncthreads();
  float alloc = fb2[tid];
  wwp[b*NM+tid] = wg*(ag*alloc + (1.0f-ag)*wcw);
}

// ---------------- K3: single pass over L; weighted row sums (R1,R2) + col sums (C2,C3) ----------------
// R1[r,j] = sum_n L[j,n]*rw[r,n]          R2[r,j] = sum_n L[j,n]*ww[n]*rw[r,n]
// C2[r,n] = sum_m L[m,n]*rw[r,m]          C3[r,n] = sum_m L[m,n]*ww[m]*rw[r,m]
__global__ __launch_bounds__(256) void k_link(
    const float* __restrict__ link, const float* __restrict__ rw,
    const float* __restrict__ wwp,
    float* __restrict__ R1, float* __restrict__ R2,
    float* __restrict__ C2, float* __restrict__ C3){
  int tile = blockIdx.x;        // 0..7 (128 rows each)
  int b = blockIdx.y;
  int tid = threadIdx.x; int lane = tid & 63; int wv = tid >> 6;
  int c0 = wv*256 + lane*4;     // this lane's 4 columns
  __shared__ float rowacc[128][4][8];   // [row][wave][R1x4,R2x4]
  float g[NR][4], h[NR][4];
  #pragma unroll
  for(int r=0;r<NR;r++){
    #pragma unroll
    for(int e=0;e<4;e++){
      float gv = rw[(b*NR+r)*NM + c0+e];
      g[r][e]=gv; h[r][e]=gv*wwp[b*NM+c0+e];
    }
  }
  float c2a[NR][4]={}, c3a[NR][4]={};
  int j0 = tile*128;
  const float* Lb = link + ((size_t)b<<20);
  for(int jr=0;jr<128;jr++){
    int row = j0 + jr;
    const float4 Lv = *(const float4*)(Lb + (size_t)row*NM + c0);
    float le[4] = {Lv.x, Lv.y, Lv.z, Lv.w};
    float wwrow = wwp[b*NM+row];
    float rp[NR], rp2[NR];
    #pragma unroll
    for(int r=0;r<NR;r++){
      float gg = rw[(b*NR+r)*NM + row];
      float hh = gg*wwrow;
      float a=0.0f, a2=0.0f;
      #pragma unroll
      for(int e=0;e<4;e++){
        a  = fmaf(le[e], g[r][e], a);
        a2 = fmaf(le[e], h[r][e], a2);
        c2a[r][e] = fmaf(le[e], gg, c2a[r][e]);
        c3a[r][e] = fmaf(le[e], hh, c3a[r][e]);
      }
      rp[r]=a; rp2[r]=a2;
    }
    #pragma unroll
    for(int r=0;r<NR;r++){
      float s  = waveSum(rp[r]);
      float s2 = waveSum(rp2[r]);
      if(lane==0){ rowacc[jr][wv][r]=s; rowacc[jr][wv][4+r]=s2; }
    }
  }
  __syncthreads();
  for(int idx=tid; idx<128*8; idx+=256){
    int jr = idx>>3, q = idx&7;
    float s = rowacc[jr][0][q]+rowacc[jr][1][q]+rowacc[jr][2][q]+rowacc[jr][3][q];
    int row = j0+jr;
    if (q<4) R1[(b*NR+q)*NM+row]=s; else R2[(b*NR+(q-4))*NM+row]=s;
  }
  #pragma unroll
  for(int r=0;r<NR;r++){
    #pragma unroll
    for(int e=0;e<4;e++){
      atomicAdd(&C2[(b*NR+r)*NM + c0+e], c2a[r][e]);
      atomicAdd(&C3[(b*NR+r)*NM + c0+e], c3a[r][e]);
    }
  }
}

// ---------------- K4: read-content softmax, forward/backward finalize, read_vectors ----------------
__global__ __launch_bounds__(1024) void k_read(
    const float* __restrict__ iface, const float* __restrict__ mem,
    const float* __restrict__ link, const float* __restrict__ prec,
    const float* __restrict__ rw_old, const float* __restrict__ wwp,
    const float* __restrict__ R1, const float* __restrict__ R2,
    const float* __restrict__ C2, const float* __restrict__ C3,
    float* __restrict__ out){
  int b = blockIdx.x; int tid = threadIdx.x; int lane=tid&63, wv=tid>>6;
  __shared__ float keys[NR][NW];
  __shared__ float er[NW], wvec[NW];
  __shared__ float wwb[NM];
  __shared__ float nrw[NR][NM];
  __shared__ float red[17];
  __shared__ float scal[16];   // [0..3]=Pr, [4..7]=Kr, [8..11]=keynorm, [12..15]=strength
  __shared__ float rm[NR][3];
  __shared__ float accb[16][NR][NW];
  const float* ifb = iface + b*NIF;
  if (tid < 256){ int r=tid>>6, k=tid&63; keys[r][k] = ifb[r*NW+k]; }
  if (tid >= 256 && tid < 320){ int k=tid-256; er[k]=sigmoidf_(ifb[325+k]); wvec[k]=ifb[389+k]; }
  wwb[tid] = wwp[b*NM+tid];
  if (tid == 0){
    // read modes: softmax over r (axis=1), logits at 458 + r*3 + mode
    for(int mo=0;mo<3;mo++){
      float x0=ifb[458+0*3+mo], x1=ifb[458+1*3+mo], x2=ifb[458+2*3+mo], x3=ifb[458+3*3+mo];
      float mx = fmaxf(fmaxf(x0,x1),fmaxf(x2,x3));
      float e0=expf(x0-mx),e1=expf(x1-mx),e2=expf(x2-mx),e3=expf(x3-mx);
      float s=e0+e1+e2+e3;
      rm[0][mo]=e0/s; rm[1][mo]=e1/s; rm[2][mo]=e2/s; rm[3][mo]=e3/s;
    }
  }
  __syncthreads();
  if (tid < NR){
    float knv=0; for(int k=0;k<NW;k++){ float t=keys[tid][k]; knv += t*t; }
    scal[8+tid]  = sqrtf(knv);
    scal[12+tid] = softplusf_(1.0f + fmaxf(ifb[256+tid],0.0f));
  }
  int j = tid;
  float pj  = prec[b*NM+j];
  float wwj = wwb[j];
  float rwv[NR];
  #pragma unroll
  for(int r=0;r<NR;r++) rwv[r]=rw_old[(b*NR+r)*NM+j];
  // Pr[r] = sum_n prec[n]*rw[r,n];  Kr[r] = sum_n ww[n]*rw[r,n]
  for(int q=0;q<8;q++){
    float v = (q<4)? pj*rwv[q] : wwj*rwv[q-4];
    float s = waveSum(v);
    if(lane==0) red[wv]=s;
    __syncthreads();
    if(tid==0){ float ss=0; for(int i=0;i<16;i++) ss+=red[i]; scal[q]=ss; }
    __syncthreads();
  }
  // Phase A: new_memory row on the fly -> content logits
  const float* mrow = mem + ((size_t)b*NM+j)*NW;
  float dots[NR]={0,0,0,0}; float nrm=0.0f;
  for(int k=0;k<NW;k++){
    float nmv = fmaf(mrow[k], (1.0f - wwj*er[k]), wwj*wvec[k]);
    nrm = fmaf(nmv,nmv,nrm);
    #pragma unroll
    for(int r=0;r<NR;r++) dots[r] = fmaf(nmv, keys[r][k], dots[r]);
  }
  float inv = 1.0f/(sqrtf(nrm)+DELTA);
  float cw[NR];
  for(int r=0;r<NR;r++){
    float logit = scal[12+r]*dots[r]*inv/(scal[8+r]+DELTA);
    float m1 = waveMax(logit); if(lane==0) red[wv]=m1; __syncthreads();
    if(tid==0){ float mm=red[0]; for(int i=1;i<16;i++) mm=fmaxf(mm,red[i]); red[16]=mm; } __syncthreads();
    float e = expf(logit - red[16]);
    float s1 = waveSum(e); if(lane==0) red[wv]=s1; __syncthreads();
    if(tid==0){ float ss=0; for(int i=0;i<16;i++) ss+=red[i]; red[16]=ss; } __syncthreads();
    cw[r] = e/red[16];
    __syncthreads();
  }
  // Phase B: forward/backward with diagonal + scalar corrections; combine with read modes
  float Ljj = link[((size_t)b<<20) + (size_t)j*(NM+1)];
  #pragma unroll
  for(int r=0;r<NR;r++){
    float r1 = R1[(b*NR+r)*NM+j], r2 = R2[(b*NR+r)*NM+j];
    float cc2 = C2[(b*NR+r)*NM+j], cc3 = C3[(b*NR+r)*NM+j];
    float grj = rwv[r];
    float fwd = (1.0f-wwj)*(r1 - Ljj*grj) - (r2 - Ljj*wwj*grj) + wwj*(scal[r] - pj*grj);
    float bwd = (cc2 - cc3) - Ljj*grj*(1.0f-wwj) - wwj*(cc2 - Ljj*grj) + pj*(scal[4+r] - wwj*grj);
    nrw[r][j] = rm[r][0]*bwd + rm[r][1]*fwd + rm[r][2]*cw[r];
  }
  __syncthreads();
  // Phase C: read_vectors[r,w] = sum_j nrw[r,j]*new_memory[j,w]
  int w = lane;
  float erw = er[w], wvw = wvec[w];
  float acc[NR]={0,0,0,0};
  int jbase = wv*64;
  for(int jj=0;jj<64;jj++){
    int jr = jbase+jj;
    float wwr = wwb[jr];
    float nmv = fmaf(mem[((size_t)b*NM+jr)*NW + w], (1.0f - wwr*erw), wwr*wvw);
    #pragma unroll
    for(int r=0;r<NR;r++) acc[r] = fmaf(nrw[r][jr], nmv, acc[r]);
  }
  #pragma unroll
  for(int r=0;r<NR;r++) accb[wv][r][w] = acc[r];
  __syncthreads();
  if (tid < 256){
    int r = tid>>6, k = tid&63;
    float s=0;
    for(int v=0;v<16;v++) s += accb[v][r][k];
    out[b*NR*NW + r*NW + k] = s;
  }
}

extern "C" void kernel_launch(void* const* d_in, const int* in_sizes, int n_in,
                              void* d_out, int out_size, void* d_ws, size_t ws_size,
                              hipStream_t stream) {
  (void)in_sizes; (void)n_in; (void)out_size; (void)ws_size;
  const float* xi   = (const float*)d_in[0];
  const float* Wm   = (const float*)d_in[1];
  const float* bW   = (const float*)d_in[2];
  const float* mem  = (const float*)d_in[3];
  const float* link = (const float*)d_in[4];
  const float* prec = (const float*)d_in[5];
  const float* rw   = (const float*)d_in[6];
  const float* wwo  = (const float*)d_in[7];
  const float* uv   = (const float*)d_in[8];
  float* out = (float*)d_out;
  float* ws  = (float*)d_ws;
  float* iface = ws;                 // 64*471 = 30144 (pad to 30208)
  float* wwp   = ws + 30208;         // 65536
  float* R1    = wwp + 65536;        // 262144
  float* R2    = R1 + 262144;        // 262144
  float* C2    = R2 + 262144;        // 262144
  float* C3    = C2 + 262144;        // 262144
  hipMemsetAsync(C2, 0, 2*262144*sizeof(float), stream);
  k_iface<<<NB, 256, 0, stream>>>(xi, Wm, bW, iface);
  k_write<<<NB, 1024, 0, stream>>>(iface, mem, rw, wwo, uv, wwp);
  k_link<<<dim3(8, NB), 256, 0, stream>>>(link, rw, wwp, R1, R2, C2, C3);
  k_read<<<NB, 1024, 0, stream>>>(iface, mem, link, prec, rw, wwp, R1, R2, C2, C3, out);
}

// Round 2
// 295.432 us; speedup vs baseline: 1.3179x; 1.3179x over previous
//
#include <hip/hip_runtime.h>

#define DELTA 1e-6f

// sizes: b=64, m=1024, w=64, r=4, d=512, iface=471
#define NB 64
#define NM 1024
#define NW 64
#define NR 4
#define ND 512
#define NIF 471

__device__ __forceinline__ float sigmoidf_(float x){ return 1.0f/(1.0f+expf(-x)); }
__device__ __forceinline__ float softplusf_(float x){ return fmaxf(x,0.0f) + log1pf(expf(-fabsf(x))); }

__device__ __forceinline__ float waveSum(float v){
  #pragma unroll
  for(int o=32;o>0;o>>=1) v += __shfl_down(v,o,64);
  return v;
}
__device__ __forceinline__ float waveMax(float v){
  #pragma unroll
  for(int o=32;o>0;o>>=1) v = fmaxf(v, __shfl_down(v,o,64));
  return v;
}
__device__ __forceinline__ float sel4_(float p0,float p1,float p2,float p3,int q){
  float a = (q&1)? p1 : p0;
  float b = (q&1)? p3 : p2;
  return (q&2)? b : a;
}

// ---------------- K1: iface = xi @ W + bW ----------------
__global__ __launch_bounds__(256) void k_iface(const float* __restrict__ xi,
                                               const float* __restrict__ Wm,
                                               const float* __restrict__ bW,
                                               float* __restrict__ iface){
  int b = blockIdx.x;
  __shared__ float xs[ND];
  for(int k=threadIdx.x;k<ND;k+=256) xs[k]=xi[b*ND+k];
  __syncthreads();
  for(int c=threadIdx.x;c<NIF;c+=256){
    float acc = bW[c];
    #pragma unroll 4
    for(int k=0;k<ND;k++) acc = fmaf(xs[k], Wm[k*NIF+c], acc);
    iface[b*NIF+c]=acc;
  }
}

// ---------------- K2: usage/psi, write-content softmax, allocation (sort), new_write_w ----------------
__global__ __launch_bounds__(1024) void k_write(
    const float* __restrict__ iface, const float* __restrict__ mem,
    const float* __restrict__ rw_old, const float* __restrict__ ww_old,
    const float* __restrict__ uv, float* __restrict__ wwp){
  int b = blockIdx.x; int tid = threadIdx.x;
  int lane = tid & 63, wv = tid >> 6;
  __shared__ float wkey[NW];
  __shared__ unsigned long long skey[NM];
  __shared__ float fb[NM];
  __shared__ float fb2[NM];
  __shared__ float red[17];
  const float* ifb = iface + b*NIF;
  if (tid < NW) wkey[tid] = ifb[260+tid];
  __syncthreads();
  float sw = softplusf_(1.0f + fmaxf(ifb[324],0.0f));
  float ag = sigmoidf_(ifb[457]);
  float wg = sigmoidf_(ifb[458]);
  float fg0=sigmoidf_(ifb[453]), fg1=sigmoidf_(ifb[454]);
  float fg2=sigmoidf_(ifb[455]), fg3=sigmoidf_(ifb[456]);
  float kn=0.0f;
  for(int k=0;k<NW;k++){ float t=wkey[k]; kn += t*t; }
  kn = sqrtf(kn);
  int j = tid;
  float u0  = uv[b*NM+j];
  float wwo = ww_old[b*NM+j];
  float usage = u0 + (1.0f-u0)*(1.0f - (1.0f-wwo));
  float psi = (1.0f - fg0*rw_old[(b*NR+0)*NM+j])
            * (1.0f - fg1*rw_old[(b*NR+1)*NM+j])
            * (1.0f - fg2*rw_old[(b*NR+2)*NM+j])
            * (1.0f - fg3*rw_old[(b*NR+3)*NM+j]);
  usage *= psi;
  float dot=0.0f, nrm=0.0f;
  const float* mrow = mem + ((size_t)b*NM + j)*NW;
  for(int k=0;k<NW;k++){ float mv=mrow[k]; dot = fmaf(mv,wkey[k],dot); nrm = fmaf(mv,mv,nrm); }
  float logit = sw * dot / ((sqrtf(nrm)+DELTA)*(kn+DELTA));
  float m1 = waveMax(logit); if(lane==0) red[wv]=m1; __syncthreads();
  if(tid==0){ float mm=red[0]; for(int i=1;i<16;i++) mm=fmaxf(mm,red[i]); red[16]=mm; } __syncthreads();
  float e = expf(logit - red[16]);
  float s1 = waveSum(e); if(lane==0) red[wv]=s1; __syncthreads();
  if(tid==0){ float ss=0; for(int i=0;i<16;i++) ss+=red[i]; red[16]=ss; } __syncthreads();
  float wcw = e/red[16];
  float u = DELTA + (1.0f-DELTA)*usage;
  skey[tid] = ((unsigned long long)__float_as_uint(u) << 32) | (unsigned)tid;
  __syncthreads();
  for(int k2=2;k2<=NM;k2<<=1){
    for(int jj=k2>>1;jj>0;jj>>=1){
      int ixj = tid ^ jj;
      if (ixj > tid){
        unsigned long long a=skey[tid], c=skey[ixj];
        bool asc = ((tid & k2)==0);
        bool doswap = asc ? (a>c) : (a<c);
        if (doswap){ skey[tid]=c; skey[ixj]=a; }
      }
      __syncthreads();
    }
  }
  float su = __uint_as_float((unsigned)(skey[tid]>>32));
  int phi  = (int)(skey[tid] & 0xffffffffu);
  fb[tid] = su; __syncthreads();
  for(int d=1; d<NM; d<<=1){
    float o = (tid>=d)? fb[tid-d] : 1.0f;
    __syncthreads();
    fb[tid] *= o;
    __syncthreads();
  }
  float salloc = (1.0f - su)*fb[tid];
  fb2[phi] = salloc;
  __syncthreads();
  float alloc = fb2[tid];
  wwp[b*NM+tid] = wg*(ag*alloc + (1.0f-ag)*wcw);
}

// ---------------- K3: single pass over L ----------------
// RF[r,j] = sum_n L[j,n]*((1-ww[j])*rw[r,n] - ww[n]*rw[r,n])   (fwd partial, pre-combined)
// C2[r,n] = sum_m L[m,n]*rw[r,m]          C3[r,n] = sum_m L[m,n]*ww[m]*rw[r,m]
__global__ __launch_bounds__(256) void k_link(
    const float* __restrict__ link, const float* __restrict__ rw,
    const float* __restrict__ wwp,
    float* __restrict__ RF,
    float* __restrict__ C2, float* __restrict__ C3){
  int tile = blockIdx.x;        // 0..15 (64 rows each)
  int b = blockIdx.y;
  int tid = threadIdx.x; int lane = tid & 63; int wv = tid >> 6;
  int c0 = wv*256 + lane*4;     // this lane's 4 columns
  __shared__ float s_rw[NR*NM];     // 16 KB
  __shared__ float s_ww[NM];        // 4 KB
  __shared__ float rowacc[64][4][4];// 4 KB
  for(int idx=tid; idx<NR*NM; idx+=256) s_rw[idx] = rw[b*NR*NM + idx];
  for(int idx=tid; idx<NM; idx+=256)   s_ww[idx] = wwp[b*NM + idx];
  __syncthreads();
  float g[NR][4], h[NR][4];
  #pragma unroll
  for(int r=0;r<NR;r++){
    #pragma unroll
    for(int e=0;e<4;e++){
      float gv = s_rw[r*NM + c0+e];
      g[r][e]=gv; h[r][e]=gv*s_ww[c0+e];
    }
  }
  float c2a[NR][4]={}, c3a[NR][4]={};
  int j0 = tile*64;
  const float* Lb = link + ((size_t)b<<20);
  for(int jr=0;jr<64;jr+=2){
    int row0 = j0 + jr, row1 = row0 + 1;
    const float4 Lv0 = *(const float4*)(Lb + (size_t)row0*NM + c0);
    const float4 Lv1 = *(const float4*)(Lb + (size_t)row1*NM + c0);
    float le0[4] = {Lv0.x, Lv0.y, Lv0.z, Lv0.w};
    float le1[4] = {Lv1.x, Lv1.y, Lv1.z, Lv1.w};
    float ww0 = s_ww[row0], ww1 = s_ww[row1];
    float cf0 = 1.0f - ww0,  cf1 = 1.0f - ww1;
    float p0[4]={0,0,0,0}, p1[4]={0,0,0,0};
    #pragma unroll
    for(int r=0;r<NR;r++){
      float gg0 = s_rw[r*NM + row0];
      float gg1 = s_rw[r*NM + row1];
      float hh0 = gg0*ww0, hh1 = gg1*ww1;
      #pragma unroll
      for(int e=0;e<4;e++){
        float t0 = fmaf(cf0, g[r][e], -h[r][e]);
        float t1 = fmaf(cf1, g[r][e], -h[r][e]);
        p0[r] = fmaf(le0[e], t0, p0[r]);
        p1[r] = fmaf(le1[e], t1, p1[r]);
        c2a[r][e] = fmaf(le0[e], gg0, c2a[r][e]);
        c3a[r][e] = fmaf(le0[e], hh0, c3a[r][e]);
        c2a[r][e] = fmaf(le1[e], gg1, c2a[r][e]);
        c3a[r][e] = fmaf(le1[e], hh1, c3a[r][e]);
      }
    }
    // batched reduction: 4 values/row, 2 rows interleaved
    #pragma unroll
    for(int st=1; st<4; st<<=1){
      #pragma unroll
      for(int r=0;r<NR;r++){
        p0[r] += __shfl_xor(p0[r], st, 64);
        p1[r] += __shfl_xor(p1[r], st, 64);
      }
    }
    int q = lane & 3;
    float s0 = sel4_(p0[0],p0[1],p0[2],p0[3], q);
    float s1 = sel4_(p1[0],p1[1],p1[2],p1[3], q);
    #pragma unroll
    for(int st=4; st<64; st<<=1){
      s0 += __shfl_xor(s0, st, 64);
      s1 += __shfl_xor(s1, st, 64);
    }
    if (lane < 4){
      rowacc[jr  ][wv][lane] = s0;
      rowacc[jr+1][wv][lane] = s1;
    }
  }
  __syncthreads();
  if (tid < 256){
    int row = tid>>2, rr = tid&3;
    float s = rowacc[row][0][rr]+rowacc[row][1][rr]+rowacc[row][2][rr]+rowacc[row][3][rr];
    RF[(b*NR+rr)*NM + j0+row] = s;
  }
  #pragma unroll
  for(int r=0;r<NR;r++){
    #pragma unroll
    for(int e=0;e<4;e++){
      atomicAdd(&C2[(b*NR+r)*NM + c0+e], c2a[r][e]);
      atomicAdd(&C3[(b*NR+r)*NM + c0+e], c3a[r][e]);
    }
  }
}

// ---------------- K4: read-content softmax, forward/backward finalize, read_vectors ----------------
__global__ __launch_bounds__(1024) void k_read(
    const float* __restrict__ iface, const float* __restrict__ mem,
    const float* __restrict__ link, const float* __restrict__ prec,
    const float* __restrict__ rw_old, const float* __restrict__ wwp,
    const float* __restrict__ RF,
    const float* __restrict__ C2, const float* __restrict__ C3,
    float* __restrict__ out){
  int b = blockIdx.x; int tid = threadIdx.x; int lane=tid&63, wv=tid>>6;
  __shared__ float keys[NR][NW];
  __shared__ float er[NW], wvec[NW];
  __shared__ float wwb[NM];
  __shared__ float nrw[NR][NM];
  __shared__ float red[17];
  __shared__ float scal[16];   // [0..3]=Pr, [4..7]=Kr, [8..11]=keynorm, [12..15]=strength
  __shared__ float rm[NR][3];
  __shared__ float accb[16][NR][NW];
  const float* ifb = iface + b*NIF;
  if (tid < 256){ int r=tid>>6, k=tid&63; keys[r][k] = ifb[r*NW+k]; }
  if (tid >= 256 && tid < 320){ int k=tid-256; er[k]=sigmoidf_(ifb[325+k]); wvec[k]=ifb[389+k]; }
  wwb[tid] = wwp[b*NM+tid];
  if (tid == 0){
    for(int mo=0;mo<3;mo++){
      float x0=ifb[458+0*3+mo], x1=ifb[458+1*3+mo], x2=ifb[458+2*3+mo], x3=ifb[458+3*3+mo];
      float mx = fmaxf(fmaxf(x0,x1),fmaxf(x2,x3));
      float e0=expf(x0-mx),e1=expf(x1-mx),e2=expf(x2-mx),e3=expf(x3-mx);
      float s=e0+e1+e2+e3;
      rm[0][mo]=e0/s; rm[1][mo]=e1/s; rm[2][mo]=e2/s; rm[3][mo]=e3/s;
    }
  }
  __syncthreads();
  if (tid < NR){
    float knv=0; for(int k=0;k<NW;k++){ float t=keys[tid][k]; knv += t*t; }
    scal[8+tid]  = sqrtf(knv);
    scal[12+tid] = softplusf_(1.0f + fmaxf(ifb[256+tid],0.0f));
  }
  int j = tid;
  float pj  = prec[b*NM+j];
  float wwj = wwb[j];
  float rwv[NR];
  #pragma unroll
  for(int r=0;r<NR;r++) rwv[r]=rw_old[(b*NR+r)*NM+j];
  for(int q=0;q<8;q++){
    float v = (q<4)? pj*rwv[q] : wwj*rwv[q-4];
    float s = waveSum(v);
    if(lane==0) red[wv]=s;
    __syncthreads();
    if(tid==0){ float ss=0; for(int i=0;i<16;i++) ss+=red[i]; scal[q]=ss; }
    __syncthreads();
  }
  const float* mrow = mem + ((size_t)b*NM+j)*NW;
  float dots[NR]={0,0,0,0}; float nrm=0.0f;
  for(int k=0;k<NW;k++){
    float nmv = fmaf(mrow[k], (1.0f - wwj*er[k]), wwj*wvec[k]);
    nrm = fmaf(nmv,nmv,nrm);
    #pragma unroll
    for(int r=0;r<NR;r++) dots[r] = fmaf(nmv, keys[r][k], dots[r]);
  }
  float inv = 1.0f/(sqrtf(nrm)+DELTA);
  float cw[NR];
  for(int r=0;r<NR;r++){
    float logit = scal[12+r]*dots[r]*inv/(scal[8+r]+DELTA);
    float m1 = waveMax(logit); if(lane==0) red[wv]=m1; __syncthreads();
    if(tid==0){ float mm=red[0]; for(int i=1;i<16;i++) mm=fmaxf(mm,red[i]); red[16]=mm; } __syncthreads();
    float e = expf(logit - red[16]);
    float s1 = waveSum(e); if(lane==0) red[wv]=s1; __syncthreads();
    if(tid==0){ float ss=0; for(int i=0;i<16;i++) ss+=red[i]; red[16]=ss; } __syncthreads();
    cw[r] = e/red[16];
    __syncthreads();
  }
  float Ljj = link[((size_t)b<<20) + (size_t)j*(NM+1)];
  #pragma unroll
  for(int r=0;r<NR;r++){
    float F  = RF[(b*NR+r)*NM+j];
    float cc2 = C2[(b*NR+r)*NM+j], cc3 = C3[(b*NR+r)*NM+j];
    float grj = rwv[r];
    float fwd = F - Ljj*grj*(1.0f-2.0f*wwj) + wwj*(scal[r] - pj*grj);
    float bwd = (cc2 - cc3) - Ljj*grj*(1.0f-wwj) - wwj*(cc2 - Ljj*grj) + pj*(scal[4+r] - wwj*grj);
    nrw[r][j] = rm[r][0]*bwd + rm[r][1]*fwd + rm[r][2]*cw[r];
  }
  __syncthreads();
  int w = lane;
  float erw = er[w], wvw = wvec[w];
  float acc[NR]={0,0,0,0};
  int jbase = wv*64;
  for(int jj=0;jj<64;jj++){
    int jr = jbase+jj;
    float wwr = wwb[jr];
    float nmv = fmaf(mem[((size_t)b*NM+jr)*NW + w], (1.0f - wwr*erw), wwr*wvw);
    #pragma unroll
    for(int r=0;r<NR;r++) acc[r] = fmaf(nrw[r][jr], nmv, acc[r]);
  }
  #pragma unroll
  for(int r=0;r<NR;r++) accb[wv][r][w] = acc[r];
  __syncthreads();
  if (tid < 256){
    int r = tid>>6, k = tid&63;
    float s=0;
    for(int v=0;v<16;v++) s += accb[v][r][k];
    out[b*NR*NW + r*NW + k] = s;
  }
}

extern "C" void kernel_launch(void* const* d_in, const int* in_sizes, int n_in,
                              void* d_out, int out_size, void* d_ws, size_t ws_size,
                              hipStream_t stream) {
  (void)in_sizes; (void)n_in; (void)out_size; (void)ws_size;
  const float* xi   = (const float*)d_in[0];
  const float* Wm   = (const float*)d_in[1];
  const float* bW   = (const float*)d_in[2];
  const float* mem  = (const float*)d_in[3];
  const float* link = (const float*)d_in[4];
  const float* prec = (const float*)d_in[5];
  const float* rw   = (const float*)d_in[6];
  const float* wwo  = (const float*)d_in[7];
  const float* uv   = (const float*)d_in[8];
  float* out = (float*)d_out;
  float* ws  = (float*)d_ws;
  float* iface = ws;                 // 64*471 -> pad 30208
  float* wwp   = ws + 30208;         // 65536
  float* RF    = wwp + 65536;        // 262144
  float* C2    = RF + 262144;        // 262144
  float* C3    = C2 + 262144;        // 262144
  hipMemsetAsync(C2, 0, 2*262144*sizeof(float), stream);
  k_iface<<<NB, 256, 0, stream>>>(xi, Wm, bW, iface);
  k_write<<<NB, 1024, 0, stream>>>(iface, mem, rw, wwo, uv, wwp);
  k_link<<<dim3(16, NB), 256, 0, stream>>>(link, rw, wwp, RF, C2, C3);
  k_read<<<NB, 1024, 0, stream>>>(iface, mem, link, prec, rw, wwp, RF, C2, C3, out);
}